// Round 1
// baseline (872.907 us; speedup 1.0000x reference)
//
#include <hip/hip_runtime.h>

// Problem constants (fixed by the reference file).
#define D_DIM    512
#define B_DIM    64
#define L_DIM    2048
#define NBLK1    256       // phase-1 blocks (1 per CU; 128 KiB LDS each)
#define THREADS1 512       // one thread per column d
#define THREADS2 256
#define LTILE    128       // l-rows per phase-2 block

// ---------------------------------------------------------------------------
// Phase 1: segment-sum. Each block owns a contiguous chunk of nodes and a full
// [B, D] accumulator in LDS (128 KiB). Thread t exclusively owns column d = t,
// so no cross-thread conflicts exist; LDS atomicAdd (ds_add_f32, no return) is
// used purely to break the compiler's conservative RMW dependency chain on
// dynamically-indexed LDS.
// ---------------------------------------------------------------------------
__global__ __launch_bounds__(THREADS1)
void seg_sum_kernel(const float* __restrict__ g, const int* __restrict__ tp,
                    float* __restrict__ x, int N, int chunk) {
    __shared__ float acc[B_DIM * D_DIM];   // 128 KiB
    __shared__ int   pos[2 * 512];         // chunk <= 512 nodes -> <=1024 ints
    const int tid = threadIdx.x;

    for (int i = tid; i < B_DIM * D_DIM; i += THREADS1) acc[i] = 0.0f;

    int start = blockIdx.x * chunk;
    int end   = start + chunk; if (end > N) end = N;
    int n     = end - start;
    // Stage this chunk's positions once (they are wave-uniform per node).
    for (int i = tid; i < 2 * n; i += THREADS1) pos[i] = tp[2 * start + i];
    __syncthreads();

    const float* gp = g + (size_t)start * D_DIM + tid;

    int i = 0;
    for (; i + 4 <= n; i += 4) {
        // 4 independent global loads in flight per wave (latency hiding).
        float v0 = gp[(size_t)(i + 0) * D_DIM];
        float v1 = gp[(size_t)(i + 1) * D_DIM];
        float v2 = gp[(size_t)(i + 2) * D_DIM];
        float v3 = gp[(size_t)(i + 3) * D_DIM];
        int p0a = pos[2*i + 0], p0b = pos[2*i + 1];
        int p1a = pos[2*i + 2], p1b = pos[2*i + 3];
        int p2a = pos[2*i + 4], p2b = pos[2*i + 5];
        int p3a = pos[2*i + 6], p3b = pos[2*i + 7];
        atomicAdd(&acc[p0a * D_DIM + tid], v0);
        atomicAdd(&acc[p0b * D_DIM + tid], v0);
        atomicAdd(&acc[p1a * D_DIM + tid], v1);
        atomicAdd(&acc[p1b * D_DIM + tid], v1);
        atomicAdd(&acc[p2a * D_DIM + tid], v2);
        atomicAdd(&acc[p2b * D_DIM + tid], v2);
        atomicAdd(&acc[p3a * D_DIM + tid], v3);
        atomicAdd(&acc[p3b * D_DIM + tid], v3);
    }
    for (; i < n; ++i) {
        float v = gp[(size_t)i * D_DIM];
        atomicAdd(&acc[pos[2*i + 0] * D_DIM + tid], v);
        atomicAdd(&acc[pos[2*i + 1] * D_DIM + tid], v);
    }
    __syncthreads();

    // Flush block-partial to global x (device-scope float atomics).
    for (int j = tid; j < B_DIM * D_DIM; j += THREADS1) {
        float v = acc[j];
        if (v != 0.0f) atomicAdd(&x[j], v);
    }
}

// ---------------------------------------------------------------------------
// Phase 2: broadcast x [B, D] -> out [B, L, D]. Each thread loads its float4
// of x exactly once and streams LTILE/2 coalesced dwordx4 stores. 128 lanes
// cover one full 2 KB row of D.
// ---------------------------------------------------------------------------
__global__ __launch_bounds__(THREADS2)
void bcast_kernel(const float* __restrict__ x, float4* __restrict__ out) {
    const int tiles_per_b = L_DIM / LTILE;                // 16
    int b     = blockIdx.x / tiles_per_b;
    int ltile = blockIdx.x % tiles_per_b;
    int d4    = threadIdx.x & (D_DIM / 4 - 1);            // 0..127
    int lo    = threadIdx.x >> 7;                         // 0..1

    const float4* x4 = (const float4*)x;
    float4 v = x4[b * (D_DIM / 4) + d4];

    size_t base = (size_t)b * L_DIM * (D_DIM / 4)
                + (size_t)ltile * LTILE * (D_DIM / 4)
                + d4;
    #pragma unroll 4
    for (int l = lo; l < LTILE; l += 2) {
        out[base + (size_t)l * (D_DIM / 4)] = v;
    }
}

extern "C" void kernel_launch(void* const* d_in, const int* in_sizes, int n_in,
                              void* d_out, int out_size, void* d_ws, size_t ws_size,
                              hipStream_t stream) {
    const float* g  = (const float*)d_in[0];
    const int*   tp = (const int*)d_in[1];
    float*       out = (float*)d_out;
    float*       x   = (float*)d_ws;       // [B, D] accumulator, 128 KiB

    int N = in_sizes[1] / 2;               // 100000
    int chunk = (N + NBLK1 - 1) / NBLK1;   // 391 <= 512 (pos[] capacity)

    // d_ws is poisoned 0xAA before every call: zero the accumulator.
    hipMemsetAsync(d_ws, 0, B_DIM * D_DIM * sizeof(float), stream);

    seg_sum_kernel<<<NBLK1, THREADS1, 0, stream>>>(g, tp, x, N, chunk);
    bcast_kernel<<<B_DIM * (L_DIM / LTILE), THREADS2, 0, stream>>>(x, (float4*)out);
}